// Round 12
// baseline (697.295 us; speedup 1.0000x reference)
//
#include <hip/hip_runtime.h>
#include <hip/hip_fp16.h>
#include <math.h>

// ---------------------------------------------------------------------------
// NatureCNN: conv×3 (implicit-im2col bf16 MFMA GEMMs, NHWC intermediates)
// | lin1+relu -> lin2 (bf16 MFMA) -> concat feat -> wih0 pre-act GEMMs (fp32)
// -> 2×(2-layer LSTM, L0/L1 software-pipelined) -> fused head.
// Round 12: LSTM iterations per stack 96 -> 33. Threads 0-255 run L0 step t;
// threads 256-511 run L1 step t-1 concurrently (its x-input h0out(t-1) IS the
// h0[t&1] buffer L0 reads at t). L1a batch phase eliminated. Both roles share
// one statically-indexed wreg[200] register array (disjoint-branch co-live
// arrays would spill at ~300 regs). __launch_bounds__(512,2) pins 256-VGPR.
// ---------------------------------------------------------------------------

typedef __attribute__((ext_vector_type(4))) float f32x4;
typedef __attribute__((ext_vector_type(8))) short s16x8;
typedef __attribute__((ext_vector_type(8))) unsigned short u16x8;
typedef __attribute__((ext_vector_type(4))) unsigned int u32x4;

__device__ __forceinline__ unsigned short f2bf(float f){
  union { float f; unsigned int u; } v; v.f = f;
  unsigned int r = (v.u + 0x7fffu + ((v.u >> 16) & 1u)) >> 16;
  return (unsigned short)r;
}
__device__ __forceinline__ unsigned short f2h(float f){
  return __half_as_ushort(__float2half(f));
}
__device__ __forceinline__ float sigmoidf_(float x){ return 1.0f/(1.0f+__expf(-x)); }
__device__ __forceinline__ float tanhf_(float x){
  float e = __expf(-2.0f*fabsf(x));
  float t = (1.0f - e)/(1.0f + e);
  return copysignf(t, x);
}

#if __has_builtin(__builtin_amdgcn_fdot2)
typedef _Float16 f16x2 __attribute__((ext_vector_type(2)));
__device__ __forceinline__ float dot2h(unsigned int a, unsigned int b, float c){
  union { unsigned int u; f16x2 h; } ua, ub;
  ua.u = a; ub.u = b;
  return __builtin_amdgcn_fdot2(ua.h, ub.h, c, false);
}
#else
__device__ __forceinline__ float dot2h(unsigned int a, unsigned int b, float c){
  __half2 ha = *(__half2*)&a, hb = *(__half2*)&b;
  float2 fa = __half22float2(ha), fb = __half22float2(hb);
  return c + fa.x*fb.x + fa.y*fb.y;
}
#endif

// ---------------------------------------------------------------------------
// ONE merged prep kernel (unchanged from round 11).
// ---------------------------------------------------------------------------
__global__ void prep_k(
    const float* __restrict__ data, unsigned short* __restrict__ data_bf,
    const float* __restrict__ l1w,  unsigned short* __restrict__ l1w_bf,
    const float* __restrict__ l2w,  unsigned short* __restrict__ l2w_bf,
    const float* __restrict__ c1w,  unsigned short* __restrict__ c1w_bf,
    const float* __restrict__ c2w,  unsigned short* __restrict__ c2w_bf,
    const float* __restrict__ c3w,  unsigned short* __restrict__ c3w_bf,
    const float* __restrict__ wihS, unsigned short* __restrict__ wihS_bf,
    const float* __restrict__ wihR, unsigned short* __restrict__ wihR_bf,
    const float* __restrict__ m0, const float* __restrict__ m1,
    const float* __restrict__ m2, const float* __restrict__ m3,
    const float* __restrict__ m4, const float* __restrict__ m5,
    unsigned int* __restrict__ wpk)
{
  const int job = blockIdx.y;
  const int stride = gridDim.x * blockDim.x;
  int e0 = blockIdx.x * blockDim.x + threadIdx.x;
  if (job == 0){
    for (int e = e0; e < 2048*1536; e += stride){
      int r = e / 1536, k = e - r*1536;
      data_bf[e] = (k < 1500) ? f2bf(data[(size_t)r*1500 + k]) : (unsigned short)0;
    }
  } else if (job == 1){
    for (int e = e0; e < 1024*1536; e += stride){
      int r = e / 1536, k = e - r*1536;
      l1w_bf[e] = (k < 1500) ? f2bf(l1w[(size_t)r*1500 + k]) : (unsigned short)0;
    }
  } else if (job == 2){
    for (int e = e0; e < 512*1024; e += stride) l2w_bf[e] = f2bf(l2w[e]);
  } else if (job == 3){
    for (int e = e0; e < 32*192; e += stride) c1w_bf[e] = f2bf(c1w[e]);
  } else if (job == 4){
    for (int e = e0; e < 64*512; e += stride){
      int oc = e >> 9, r = e & 511;
      int tap = r >> 5, ic = r & 31;
      c2w_bf[e] = f2bf(c2w[(size_t)oc*512 + ic*16 + tap]);
    }
  } else if (job == 5){
    for (int e = e0; e < 64*576; e += stride){
      int oc = e / 576, r = e - oc*576;
      int tap = r >> 6, ic = r & 63;
      c3w_bf[e] = f2bf(c3w[(size_t)oc*576 + ic*9 + tap]);
    }
  } else if (job == 6 || job == 7){
    const float* src = (job == 6) ? wihS : wihR;
    unsigned short* dst = (job == 6) ? wihS_bf : wihR_bf;
    for (int e = e0; e < 400*1536; e += stride){
      int g = e / 1536, k = e - g*1536;
      int ksrc = (k < 1024) ? ((k & 63)*16 + (k >> 6)) : k;
      dst[e] = f2bf(src[(size_t)g*1536 + ksrc]);
    }
  } else {
    const float* srcs[6] = {m0,m1,m2,m3,m4,m5};
    for (int e = e0; e < 6*20000; e += stride){
      int mat = e / 20000, r = e - mat*20000;
      int kk = r / 400, g = r - kk*400;
      const float* src = srcs[mat];
      unsigned int lo = f2h(src[g*100 + 2*kk]);
      unsigned int hi = f2h(src[g*100 + 2*kk + 1]);
      wpk[e] = lo | (hi << 16);
    }
  }
}

// ---------------------------------------------------------------------------
// bf16 MFMA GEMM (unchanged, passing since round 2)
// ---------------------------------------------------------------------------
template<int BM,int BN,int WAVES_M,int WAVES_N,int AMODE,int CMODE,int RELU,int NGUARD,
         int CIN,int HI,int WI,int KH,int KW,int ST,int HO,int WO>
__global__ __launch_bounds__(256) void mgemm(
    const void* __restrict__ Av, const unsigned short* __restrict__ B,
    void* __restrict__ Cv, const float* __restrict__ bias,
    int M, int N, int K, int lda, int ldc, int cstride)
{
  constexpr int BK = 64;
  constexpr int WROWS = BM / WAVES_M;
  constexpr int WCOLS = BN / WAVES_N;
  constexpr int MF = WROWS / 16;
  constexpr int NF = WCOLS / 16;
  constexpr int HOWO = HO*WO;
  __shared__ unsigned short As[BM*BK];
  __shared__ unsigned short Bs[BN*BK];
  const int tid = threadIdx.x;
  const int bm = blockIdx.x * BM;
  const int bn = blockIdx.y * BN;
  const int lane = tid & 63, w = tid >> 6;
  const int wm = w / WAVES_N, wn = w % WAVES_N;
  const int m0 = wm * WROWS, n0 = wn * WCOLS;

  f32x4 acc[MF][NF] = {};

  const int ar = tid >> 1;
  const int as0 = 4 * (tid & 1);
  const int row_g = bm + ar;
  int a_n = 0, a_oy = 0, a_ox = 0;
  if (AMODE != 0){ a_n = row_g / HOWO; int p = row_g - a_n*HOWO; a_oy = p / WO; a_ox = p - a_oy*WO; }

  for (int kt = 0; kt < K; kt += BK){
    #pragma unroll
    for (int si = 0; si < 4; ++si){
      int s = as0 + si;
      int k0 = kt + s*8;
      u16x8 val;
      if constexpr (AMODE == 0){
        val = *(const u16x8*)((const unsigned short*)Av + (size_t)row_g*lda + k0);
      } else if constexpr (AMODE == 1){
        int ic = k0 >> 6, r = k0 & 63, ky = r >> 3;
        const float* src = (const float*)Av +
            (((size_t)(a_n*CIN + ic)*HI + a_oy*ST + ky)*WI + a_ox*ST);
        f32x4 f0 = *(const f32x4*)src;
        f32x4 f1 = *(const f32x4*)(src + 4);
        val[0]=f2bf(f0[0]); val[1]=f2bf(f0[1]); val[2]=f2bf(f0[2]); val[3]=f2bf(f0[3]);
        val[4]=f2bf(f1[0]); val[5]=f2bf(f1[1]); val[6]=f2bf(f1[2]); val[7]=f2bf(f1[3]);
      } else {
        int tap = k0 / CIN, ic0 = k0 - tap*CIN;
        int ky = tap / KW, kx = tap - ky*KW;
        const unsigned short* src = (const unsigned short*)Av +
            (((size_t)(a_n*HI + a_oy*ST + ky)*WI + a_ox*ST + kx)*CIN + ic0);
        val = *(const u16x8*)src;
      }
      int phys = s ^ ((ar >> 1) & 7);
      *(u16x8*)&As[ar*BK + phys*8] = val;
    }
    if constexpr (BN == 64){
      int br = tid >> 2, bs0 = 2*(tid & 3);
      #pragma unroll
      for (int si = 0; si < 2; ++si){
        int s = bs0 + si, k0 = kt + s*8;
        int n_g = bn + br;
        u16x8 val = {};
        if (!NGUARD || n_g < N) val = *(const u16x8*)(B + (size_t)n_g*K + k0);
        int phys = s ^ ((br >> 1) & 7);
        *(u16x8*)&Bs[br*BK + phys*8] = val;
      }
    } else {
      int br = tid >> 3, s = tid & 7, k0 = kt + s*8;
      int n_g = bn + br;
      u16x8 val = {};
      if (!NGUARD || n_g < N) val = *(const u16x8*)(B + (size_t)n_g*K + k0);
      int phys = s ^ ((br >> 1) & 7);
      *(u16x8*)&Bs[br*BK + phys*8] = val;
    }
    __syncthreads();
    #pragma unroll
    for (int ks = 0; ks < 2; ++ks){
      s16x8 a[MF], b[NF];
      #pragma unroll
      for (int i = 0; i < MF; ++i){
        int row = m0 + i*16 + (lane & 15);
        int phys = (ks*4 + (lane >> 4)) ^ ((row >> 1) & 7);
        a[i] = *(const s16x8*)&As[row*BK + phys*8];
      }
      #pragma unroll
      for (int j = 0; j < NF; ++j){
        int row = n0 + j*16 + (lane & 15);
        int phys = (ks*4 + (lane >> 4)) ^ ((row >> 1) & 7);
        b[j] = *(const s16x8*)&Bs[row*BK + phys*8];
      }
      #pragma unroll
      for (int i = 0; i < MF; ++i)
        #pragma unroll
        for (int j = 0; j < NF; ++j)
          acc[i][j] = __builtin_amdgcn_mfma_f32_16x16x32_bf16(a[i], b[j], acc[i][j], 0, 0, 0);
    }
    __syncthreads();
  }

  if constexpr (CMODE == 3){
    float* Cf = (float*)Cv;
    #pragma unroll
    for (int i = 0; i < MF; ++i)
      #pragma unroll
      for (int j = 0; j < NF; ++j){
        int col = bn + n0 + j*16 + (lane & 15);
        float bv = (bias && (!NGUARD || col < N)) ? bias[col] : 0.f;
        #pragma unroll
        for (int q = 0; q < 4; ++q){
          int row = bm + m0 + i*16 + (lane >> 4)*4 + q;
          float v = acc[i][j][q] + bv;
          if (RELU) v = fmaxf(v, 0.f);
          if (!NGUARD || col < N) Cf[(size_t)row*ldc + col] = v;
        }
      }
  } else {
    unsigned short* tile = As;
    #pragma unroll
    for (int i = 0; i < MF; ++i)
      #pragma unroll
      for (int j = 0; j < NF; ++j){
        int col = n0 + j*16 + (lane & 15);
        float bv = bias ? bias[bn + col] : 0.f;
        #pragma unroll
        for (int q = 0; q < 4; ++q){
          int row = m0 + i*16 + (lane >> 4)*4 + q;
          float v = acc[i][j][q] + bv;
          if (RELU) v = fmaxf(v, 0.f);
          tile[row*BN + col] = f2bf(v);
        }
      }
    __syncthreads();
    unsigned short* Cu = (unsigned short*)Cv;
    constexpr int CHUNKS = (BM*BN)/(256*8);
    #pragma unroll
    for (int c = 0; c < CHUNKS; ++c){
      int flat = tid*8 + c*2048;
      int row = flat / BN, col = flat - (flat/BN)*BN;
      u16x8 v = *(const u16x8*)&tile[flat];
      int rg = bm + row;
      size_t addr;
      if constexpr (CMODE == 0) addr = (size_t)rg*ldc + bn + col;
      else { int n = rg >> 4, p = rg & 15; addr = (size_t)n*cstride + p*64 + col; }
      *(u16x8*)&Cu[addr] = v;
    }
  }
}

// ---------------------------------------------------------------------------
// LSTM: one block per segment; both stacks. 512 threads (8 waves).
// Threads 0-255: layer 0 (e=tid>>1, sub=tid&1; sub0 gates i,g; sub1 f,o).
// Threads 256-511: layer 1, pipelined ONE STEP BEHIND: at iter t it computes
// L1 step u=t-1, reading h1[u&1] and its x-input h0out(u)=h0[t&1] (the very
// buffer L0 reads at t). Fused dot: w1h.h1 + w1x.h0out. 33 iters/stack.
// Both roles share wreg[200] (static indices); c kept in registers (sub1).
// Head fused at the end.
// ---------------------------------------------------------------------------
__global__ __launch_bounds__(512,2) void lstm_k(
    const float* __restrict__ X0s, const float* __restrict__ X0r,
    const unsigned int* __restrict__ wpk,  // 6 x [50][400] u32 packed f16 pairs
    const float* __restrict__ s_bih0, const float* __restrict__ s_bhh0,
    const float* __restrict__ s_bih1, const float* __restrict__ s_bhh1,
    const float* __restrict__ r_bih0, const float* __restrict__ r_bhh0,
    const float* __restrict__ r_bih1, const float* __restrict__ r_bhh1,
    const float* __restrict__ f1w, const float* __restrict__ f1b,
    const float* __restrict__ f2w, const float* __restrict__ f2b,
    float* __restrict__ out)
{
  __shared__ alignas(16) unsigned int h0p[2][56];   // dbuf, 50 pairs (+pad)
  __shared__ alignas(16) unsigned int h1p[2][56];
  __shared__ float xin[200];                        // head input [outR|outS]
  __shared__ float mid[512];                        // head hidden

  const int b = blockIdx.x, tid = threadIdx.x;
  const bool isL0 = (tid < 256);
  const int tl = isL0 ? tid : (tid - 256);
  const int e = tl >> 1, sub = tl & 1;
  const bool act = (e < 100);
  const int eS = act ? e : 0;
  const int gA = sub*100 + eS;           // sub0: i-gate, sub1: f-gate
  const int gB = gA + 200;               // sub0: g-gate, sub1: o-gate

  if (tid < 56){ h0p[0][tid]=0u; h0p[1][tid]=0u; h1p[0][tid]=0u; h1p[1][tid]=0u; }
  float c0r = 0.f, c1r = 0.f;
  __syncthreads();

  #pragma unroll 1
  for (int s = 0; s < 2; ++s){
    const float* Xp = (s ? X0r : X0s) + (size_t)b*32*400;
    const unsigned int* w0P  = wpk + (size_t)(s ? 3 : 0)*20000;
    const unsigned int* w1xP = wpk + (size_t)(s ? 4 : 1)*20000;
    const unsigned int* w1hP = wpk + (size_t)(s ? 5 : 2)*20000;
    const float* bi0 = s ? r_bih0 : s_bih0;
    const float* bh0 = s ? r_bhh0 : s_bhh0;
    const float* bi1 = s ? r_bih1 : s_bih1;
    const float* bh1 = s ? r_bhh1 : s_bhh1;

    // --- per-stack setup: unified weight register file (static indices) ---
    unsigned int wreg[200];
    float bsA, bsB, xcA = 0.f, xcB = 0.f;
    if (isL0){
      #pragma unroll
      for (int p = 0; p < 50; ++p){
        wreg[p]      = w0P[p*400 + gA];
        wreg[50+p]   = w0P[p*400 + gB];
      }
      bsA = bi0[gA] + bh0[gA];
      bsB = bi0[gB] + bh0[gB];
      xcA = Xp[gA]; xcB = Xp[gB];
    } else {
      #pragma unroll
      for (int p = 0; p < 50; ++p){
        wreg[p]      = w1hP[p*400 + gA];
        wreg[50+p]   = w1hP[p*400 + gB];
        wreg[100+p]  = w1xP[p*400 + gA];
        wreg[150+p]  = w1xP[p*400 + gB];
      }
      bsA = bi1[gA] + bh1[gA];
      bsB = bi1[gB] + bh1[gB];
    }
    __syncthreads();

    // --- pipelined loop: iter t runs L0 step t (t<32) and L1 step t-1 (t>=1) ---
    #pragma unroll 1
    for (int t = 0; t < 33; ++t){
      if (isL0){
        if (t < 32){
          float xnA = 0.f, xnB = 0.f;
          if (t < 31){ xnA = Xp[(t+1)*400 + gA]; xnB = Xp[(t+1)*400 + gB]; }
          const u32x4* h4 = (const u32x4*)h0p[t & 1];
          float a0=0.f, a1=0.f, b0=0.f, b1=0.f;
          #pragma unroll
          for (int i = 0; i < 12; ++i){
            u32x4 hv = h4[i];
            a0 = dot2h(wreg[4*i+0], hv[0], a0);
            a1 = dot2h(wreg[4*i+1], hv[1], a1);
            a0 = dot2h(wreg[4*i+2], hv[2], a0);
            a1 = dot2h(wreg[4*i+3], hv[3], a1);
            b0 = dot2h(wreg[50+4*i+0], hv[0], b0);
            b1 = dot2h(wreg[50+4*i+1], hv[1], b1);
            b0 = dot2h(wreg[50+4*i+2], hv[2], b0);
            b1 = dot2h(wreg[50+4*i+3], hv[3], b1);
          }
          { u32x4 hv = h4[12];
            a0 = dot2h(wreg[48], hv[0], a0);
            a1 = dot2h(wreg[49], hv[1], a1);
            b0 = dot2h(wreg[98], hv[0], b0);
            b1 = dot2h(wreg[99], hv[1], b1);
          }
          float preA = (a0 + a1) + xcA + bsA;
          float preB = (b0 + b1) + xcB + bsB;
          float vA = sigmoidf_(preA);                       // i (sub0) / f (sub1)
          float vB = sub ? sigmoidf_(preB) : tanhf_(preB);  // o (sub1) / g (sub0)
          float send = vA * vB;                             // sub0: i*g
          float recv = __shfl_xor(send, 1);
          if (act && sub){
            c0r = vA*c0r + recv;
            float hn = vB * tanhf_(c0r);
            ((unsigned short*)h0p[(t+1) & 1])[e] = f2h(hn);
          }
          xcA = xnA; xcB = xnB;
        }
      } else {
        if (t >= 1){
          const int u = t - 1;
          const u32x4* h4 = (const u32x4*)h1p[u & 1];
          const u32x4* x4 = (const u32x4*)h0p[t & 1];     // h0out(u)
          float a0=0.f, a1=0.f, b0=0.f, b1=0.f;
          #pragma unroll
          for (int i = 0; i < 12; ++i){
            u32x4 hv = h4[i];
            a0 = dot2h(wreg[4*i+0], hv[0], a0);
            a1 = dot2h(wreg[4*i+1], hv[1], a1);
            a0 = dot2h(wreg[4*i+2], hv[2], a0);
            a1 = dot2h(wreg[4*i+3], hv[3], a1);
            b0 = dot2h(wreg[50+4*i+0], hv[0], b0);
            b1 = dot2h(wreg[50+4*i+1], hv[1], b1);
            b0 = dot2h(wreg[50+4*i+2], hv[2], b0);
            b1 = dot2h(wreg[50+4*i+3], hv[3], b1);
            u32x4 xv = x4[i];
            a0 = dot2h(wreg[100+4*i+0], xv[0], a0);
            a1 = dot2h(wreg[100+4*i+1], xv[1], a1);
            a0 = dot2h(wreg[100+4*i+2], xv[2], a0);
            a1 = dot2h(wreg[100+4*i+3], xv[3], a1);
            b0 = dot2h(wreg[150+4*i+0], xv[0], b0);
            b1 = dot2h(wreg[150+4*i+1], xv[1], b1);
            b0 = dot2h(wreg[150+4*i+2], xv[2], b0);
            b1 = dot2h(wreg[150+4*i+3], xv[3], b1);
          }
          { u32x4 hv = h4[12];
            a0 = dot2h(wreg[48], hv[0], a0);
            a1 = dot2h(wreg[49], hv[1], a1);
            b0 = dot2h(wreg[98], hv[0], b0);
            b1 = dot2h(wreg[99], hv[1], b1);
            u32x4 xv = x4[12];
            a0 = dot2h(wreg[148], xv[0], a0);
            a1 = dot2h(wreg[149], xv[1], a1);
            b0 = dot2h(wreg[198], xv[0], b0);
            b1 = dot2h(wreg[199], xv[1], b1);
          }
          float preA = (a0 + a1) + bsA;
          float preB = (b0 + b1) + bsB;
          float vA = sigmoidf_(preA);
          float vB = sub ? sigmoidf_(preB) : tanhf_(preB);
          float send = vA * vB;
          float recv = __shfl_xor(send, 1);
          if (act && sub){
            c1r = vA*c1r + recv;
            float hn = vB * tanhf_(c1r);
            ((unsigned short*)h1p[t & 1])[e] = f2h(hn);
            if (u == 31){
              if (s) xin[e] = hn;          // outR -> head cols [0,100)
              else   xin[100 + e] = hn;    // outS -> head cols [100,200)
            }
          }
        }
      }
      __syncthreads();
    }
  }

  // ------------- fused head: out[b] = relu(xin@f1w^T+b1)@f2w^T+b2 -------------
  {
    float acc = f1b[tid];
    const float* wrow = f1w + (size_t)tid*200;
    #pragma unroll 4
    for (int k = 0; k < 200; ++k) acc += xin[k]*wrow[k];
    mid[tid] = fmaxf(acc, 0.f);
  }
  __syncthreads();
  if (tid < 130){
    float acc = f2b[tid];
    const float* wrow = f2w + (size_t)tid*512;
    #pragma unroll 4
    for (int k = 0; k < 512; ++k) acc += mid[k]*wrow[k];
    out[b*130 + tid] = acc;
  }
}

extern "C" void kernel_launch(void* const* d_in, const int* in_sizes, int n_in,
                              void* d_out, int out_size, void* d_ws, size_t ws_size,
                              hipStream_t stream)
{
  const float* obs  = (const float*)d_in[0];
  const float* data = (const float*)d_in[1];
  const float* c1w = (const float*)d_in[2];  const float* c1b = (const float*)d_in[3];
  const float* c2w = (const float*)d_in[4];  const float* c2b = (const float*)d_in[5];
  const float* c3w = (const float*)d_in[6];  const float* c3b = (const float*)d_in[7];
  const float* l1w = (const float*)d_in[8];  const float* l1b = (const float*)d_in[9];
  const float* l2w = (const float*)d_in[10]; const float* l2b = (const float*)d_in[11];
  const float* s_wih0=(const float*)d_in[12]; const float* s_whh0=(const float*)d_in[13];
  const float* s_bih0=(const float*)d_in[14]; const float* s_bhh0=(const float*)d_in[15];
  const float* s_wih1=(const float*)d_in[16]; const float* s_whh1=(const float*)d_in[17];
  const float* s_bih1=(const float*)d_in[18]; const float* s_bhh1=(const float*)d_in[19];
  const float* r_wih0=(const float*)d_in[20]; const float* r_whh0=(const float*)d_in[21];
  const float* r_bih0=(const float*)d_in[22]; const float* r_bhh0=(const float*)d_in[23];
  const float* r_wih1=(const float*)d_in[24]; const float* r_whh1=(const float*)d_in[25];
  const float* r_bih1=(const float*)d_in[26]; const float* r_bhh1=(const float*)d_in[27];
  const float* f1w=(const float*)d_in[28]; const float* f1b=(const float*)d_in[29];
  const float* f2w=(const float*)d_in[30]; const float* f2b=(const float*)d_in[31];
  float* out = (float*)d_out;
  (void)in_sizes; (void)n_in; (void)out_size;

  // ---- workspace layout (bytes, 256-aligned); total ~ 67 MB ----
  char* p = (char*)d_ws;
  auto alloc = [&](size_t bytes){ void* r = (void*)p; p += (bytes + 255) & ~(size_t)255; return r; };
  unsigned short* data_bf = (unsigned short*)alloc((size_t)2048*1536*2);
  unsigned short* c1w_bf  = (unsigned short*)alloc((size_t)32*192*2);
  unsigned short* c2w_bf  = (unsigned short*)alloc((size_t)64*512*2);
  unsigned short* c3w_bf  = (unsigned short*)alloc((size_t)64*576*2);
  unsigned short* l1w_bf  = (unsigned short*)alloc((size_t)1024*1536*2);
  unsigned short* l2w_bf  = (unsigned short*)alloc((size_t)512*1024*2);
  unsigned short* wihS_bf = (unsigned short*)alloc((size_t)400*1536*2);
  unsigned short* wihR_bf = (unsigned short*)alloc((size_t)400*1536*2);
  unsigned short* conv1o  = (unsigned short*)alloc((size_t)2048*225*32*2);  // NHWC
  unsigned short* conv2o  = (unsigned short*)alloc((size_t)2048*36*64*2);   // NHWC
  unsigned short* feat    = (unsigned short*)alloc((size_t)2048*1536*2);
  unsigned short* lin1o   = (unsigned short*)alloc((size_t)2048*1024*2);
  float* X0s  = (float*)alloc((size_t)1024*400*4);
  float* X0r  = (float*)alloc((size_t)1024*400*4);
  unsigned int* wpk = (unsigned int*)alloc((size_t)6*20000*4);
  (void)ws_size;

  // ---- merged prep (1 launch) ----
  prep_k<<<dim3(512,9),256,0,stream>>>(
      data, data_bf, l1w, l1w_bf, l2w, l2w_bf, c1w, c1w_bf,
      c2w, c2w_bf, c3w, c3w_bf, s_wih0, wihS_bf, r_wih0, wihR_bf,
      s_whh0, s_wih1, s_whh1, r_whh0, r_wih1, r_whh1, wpk);

  // ---- GEMM chain (bf16 MFMA, fp32 accumulate) ----
  mgemm<128,32,4,1, 1,0,1,0, 3,64,64,8,8,4,15,15><<<dim3(3600,1),256,0,stream>>>(
      obs, c1w_bf, conv1o, c1b, 460800, 32, 192, 0, 32, 0);
  mgemm<128,64,2,2, 2,0,1,0, 32,15,15,4,4,2,6,6><<<dim3(576,1),256,0,stream>>>(
      conv1o, c2w_bf, conv2o, c2b, 73728, 64, 512, 0, 64, 0);
  mgemm<128,64,2,2, 0,0,1,0, 1,1,1,1,1,1,1,1><<<dim3(16,16),256,0,stream>>>(
      data_bf, l1w_bf, lin1o, l1b, 2048, 1024, 1536, 1536, 1024, 0);
  mgemm<128,64,2,2, 2,2,1,0, 64,6,6,3,3,1,4,4><<<dim3(256,1),256,0,stream>>>(
      conv2o, c3w_bf, feat, c3b, 32768, 64, 576, 0, 0, 1536);
  mgemm<128,64,2,2, 0,0,0,0, 1,1,1,1,1,1,1,1><<<dim3(16,8),256,0,stream>>>(
      lin1o, l2w_bf, feat + 1024, l2b, 2048, 512, 1024, 1024, 1536, 0);
  mgemm<128,64,2,2, 0,3,0,1, 1,1,1,1,1,1,1,1><<<dim3(8,7),256,0,stream>>>(
      feat, wihS_bf, X0s, (const float*)nullptr, 1024, 400, 1536, 1536, 400, 0);
  mgemm<128,64,2,2, 0,3,0,1, 1,1,1,1,1,1,1,1><<<dim3(8,7),256,0,stream>>>(
      feat + (size_t)1024*1536, wihR_bf, X0r, (const float*)nullptr, 1024, 400, 1536, 1536, 400, 0);

  // ---- sequential LSTM (pipelined L0||L1) + fused head ----
  lstm_k<<<32,512,0,stream>>>(X0s, X0r, wpk,
                              s_bih0,s_bhh0,s_bih1,s_bhh1,
                              r_bih0,r_bhh0,r_bih1,r_bhh1,
                              f1w, f1b, f2w, f2b, out);
}

// Round 13
// 331.228 us; speedup vs baseline: 2.1052x; 2.1052x over previous
//
#include <hip/hip_runtime.h>
#include <hip/hip_fp16.h>
#include <math.h>

// ---------------------------------------------------------------------------
// NatureCNN: conv×3 (implicit-im2col bf16 MFMA GEMMs, NHWC intermediates)
// | lin1+relu -> lin2 (bf16 MFMA) -> concat feat -> wih0 pre-act GEMMs (fp32)
// -> 2×(2-layer LSTM) -> fused head.
// Round 13: r11 structure (best: 331us total, lstm 165us) + VGPR pinning.
// r11's VGPR_Count=92 < the 100 declared weight regs proves the compiler
// re-loads weights inside the recurrent loop (L2 latency per step = the
// missing 4x). asm volatile("" : "+v"(w)) after the load loop pins each
// weight in a VGPR (opaque modification forbids rematerialization).
// launch_bounds(256,1) -> 512-VGPR budget, plenty.
// r12's L0/L1 pipelining reverted (launch_bounds trap -> 128 budget, spilled).
// ---------------------------------------------------------------------------

typedef __attribute__((ext_vector_type(4))) float f32x4;
typedef __attribute__((ext_vector_type(8))) short s16x8;
typedef __attribute__((ext_vector_type(8))) unsigned short u16x8;
typedef __attribute__((ext_vector_type(4))) unsigned int u32x4;

__device__ __forceinline__ unsigned short f2bf(float f){
  union { float f; unsigned int u; } v; v.f = f;
  unsigned int r = (v.u + 0x7fffu + ((v.u >> 16) & 1u)) >> 16;
  return (unsigned short)r;
}
__device__ __forceinline__ unsigned short f2h(float f){
  return __half_as_ushort(__float2half(f));
}
__device__ __forceinline__ float sigmoidf_(float x){ return 1.0f/(1.0f+__expf(-x)); }
__device__ __forceinline__ float tanhf_(float x){
  float e = __expf(-2.0f*fabsf(x));
  float t = (1.0f - e)/(1.0f + e);
  return copysignf(t, x);
}

#if __has_builtin(__builtin_amdgcn_fdot2)
typedef _Float16 f16x2 __attribute__((ext_vector_type(2)));
__device__ __forceinline__ float dot2h(unsigned int a, unsigned int b, float c){
  union { unsigned int u; f16x2 h; } ua, ub;
  ua.u = a; ub.u = b;
  return __builtin_amdgcn_fdot2(ua.h, ub.h, c, false);
}
#else
__device__ __forceinline__ float dot2h(unsigned int a, unsigned int b, float c){
  __half2 ha = *(__half2*)&a, hb = *(__half2*)&b;
  float2 fa = __half22float2(ha), fb = __half22float2(hb);
  return c + fa.x*fb.x + fa.y*fb.y;
}
#endif

// ---------------------------------------------------------------------------
// ONE merged prep kernel (unchanged from round 11).
// ---------------------------------------------------------------------------
__global__ void prep_k(
    const float* __restrict__ data, unsigned short* __restrict__ data_bf,
    const float* __restrict__ l1w,  unsigned short* __restrict__ l1w_bf,
    const float* __restrict__ l2w,  unsigned short* __restrict__ l2w_bf,
    const float* __restrict__ c1w,  unsigned short* __restrict__ c1w_bf,
    const float* __restrict__ c2w,  unsigned short* __restrict__ c2w_bf,
    const float* __restrict__ c3w,  unsigned short* __restrict__ c3w_bf,
    const float* __restrict__ wihS, unsigned short* __restrict__ wihS_bf,
    const float* __restrict__ wihR, unsigned short* __restrict__ wihR_bf,
    const float* __restrict__ m0, const float* __restrict__ m1,
    const float* __restrict__ m2, const float* __restrict__ m3,
    const float* __restrict__ m4, const float* __restrict__ m5,
    unsigned int* __restrict__ wpk)
{
  const int job = blockIdx.y;
  const int stride = gridDim.x * blockDim.x;
  int e0 = blockIdx.x * blockDim.x + threadIdx.x;
  if (job == 0){
    for (int e = e0; e < 2048*1536; e += stride){
      int r = e / 1536, k = e - r*1536;
      data_bf[e] = (k < 1500) ? f2bf(data[(size_t)r*1500 + k]) : (unsigned short)0;
    }
  } else if (job == 1){
    for (int e = e0; e < 1024*1536; e += stride){
      int r = e / 1536, k = e - r*1536;
      l1w_bf[e] = (k < 1500) ? f2bf(l1w[(size_t)r*1500 + k]) : (unsigned short)0;
    }
  } else if (job == 2){
    for (int e = e0; e < 512*1024; e += stride) l2w_bf[e] = f2bf(l2w[e]);
  } else if (job == 3){
    for (int e = e0; e < 32*192; e += stride) c1w_bf[e] = f2bf(c1w[e]);
  } else if (job == 4){
    for (int e = e0; e < 64*512; e += stride){
      int oc = e >> 9, r = e & 511;
      int tap = r >> 5, ic = r & 31;
      c2w_bf[e] = f2bf(c2w[(size_t)oc*512 + ic*16 + tap]);
    }
  } else if (job == 5){
    for (int e = e0; e < 64*576; e += stride){
      int oc = e / 576, r = e - oc*576;
      int tap = r >> 6, ic = r & 63;
      c3w_bf[e] = f2bf(c3w[(size_t)oc*576 + ic*9 + tap]);
    }
  } else if (job == 6 || job == 7){
    const float* src = (job == 6) ? wihS : wihR;
    unsigned short* dst = (job == 6) ? wihS_bf : wihR_bf;
    for (int e = e0; e < 400*1536; e += stride){
      int g = e / 1536, k = e - g*1536;
      int ksrc = (k < 1024) ? ((k & 63)*16 + (k >> 6)) : k;
      dst[e] = f2bf(src[(size_t)g*1536 + ksrc]);
    }
  } else {
    const float* srcs[6] = {m0,m1,m2,m3,m4,m5};
    for (int e = e0; e < 6*20000; e += stride){
      int mat = e / 20000, r = e - mat*20000;
      int kk = r / 400, g = r - kk*400;
      const float* src = srcs[mat];
      unsigned int lo = f2h(src[g*100 + 2*kk]);
      unsigned int hi = f2h(src[g*100 + 2*kk + 1]);
      wpk[e] = lo | (hi << 16);
    }
  }
}

// ---------------------------------------------------------------------------
// bf16 MFMA GEMM (unchanged, passing since round 2)
// ---------------------------------------------------------------------------
template<int BM,int BN,int WAVES_M,int WAVES_N,int AMODE,int CMODE,int RELU,int NGUARD,
         int CIN,int HI,int WI,int KH,int KW,int ST,int HO,int WO>
__global__ __launch_bounds__(256) void mgemm(
    const void* __restrict__ Av, const unsigned short* __restrict__ B,
    void* __restrict__ Cv, const float* __restrict__ bias,
    int M, int N, int K, int lda, int ldc, int cstride)
{
  constexpr int BK = 64;
  constexpr int WROWS = BM / WAVES_M;
  constexpr int WCOLS = BN / WAVES_N;
  constexpr int MF = WROWS / 16;
  constexpr int NF = WCOLS / 16;
  constexpr int HOWO = HO*WO;
  __shared__ unsigned short As[BM*BK];
  __shared__ unsigned short Bs[BN*BK];
  const int tid = threadIdx.x;
  const int bm = blockIdx.x * BM;
  const int bn = blockIdx.y * BN;
  const int lane = tid & 63, w = tid >> 6;
  const int wm = w / WAVES_N, wn = w % WAVES_N;
  const int m0 = wm * WROWS, n0 = wn * WCOLS;

  f32x4 acc[MF][NF] = {};

  const int ar = tid >> 1;
  const int as0 = 4 * (tid & 1);
  const int row_g = bm + ar;
  int a_n = 0, a_oy = 0, a_ox = 0;
  if (AMODE != 0){ a_n = row_g / HOWO; int p = row_g - a_n*HOWO; a_oy = p / WO; a_ox = p - a_oy*WO; }

  for (int kt = 0; kt < K; kt += BK){
    #pragma unroll
    for (int si = 0; si < 4; ++si){
      int s = as0 + si;
      int k0 = kt + s*8;
      u16x8 val;
      if constexpr (AMODE == 0){
        val = *(const u16x8*)((const unsigned short*)Av + (size_t)row_g*lda + k0);
      } else if constexpr (AMODE == 1){
        int ic = k0 >> 6, r = k0 & 63, ky = r >> 3;
        const float* src = (const float*)Av +
            (((size_t)(a_n*CIN + ic)*HI + a_oy*ST + ky)*WI + a_ox*ST);
        f32x4 f0 = *(const f32x4*)src;
        f32x4 f1 = *(const f32x4*)(src + 4);
        val[0]=f2bf(f0[0]); val[1]=f2bf(f0[1]); val[2]=f2bf(f0[2]); val[3]=f2bf(f0[3]);
        val[4]=f2bf(f1[0]); val[5]=f2bf(f1[1]); val[6]=f2bf(f1[2]); val[7]=f2bf(f1[3]);
      } else {
        int tap = k0 / CIN, ic0 = k0 - tap*CIN;
        int ky = tap / KW, kx = tap - ky*KW;
        const unsigned short* src = (const unsigned short*)Av +
            (((size_t)(a_n*HI + a_oy*ST + ky)*WI + a_ox*ST + kx)*CIN + ic0);
        val = *(const u16x8*)src;
      }
      int phys = s ^ ((ar >> 1) & 7);
      *(u16x8*)&As[ar*BK + phys*8] = val;
    }
    if constexpr (BN == 64){
      int br = tid >> 2, bs0 = 2*(tid & 3);
      #pragma unroll
      for (int si = 0; si < 2; ++si){
        int s = bs0 + si, k0 = kt + s*8;
        int n_g = bn + br;
        u16x8 val = {};
        if (!NGUARD || n_g < N) val = *(const u16x8*)(B + (size_t)n_g*K + k0);
        int phys = s ^ ((br >> 1) & 7);
        *(u16x8*)&Bs[br*BK + phys*8] = val;
      }
    } else {
      int br = tid >> 3, s = tid & 7, k0 = kt + s*8;
      int n_g = bn + br;
      u16x8 val = {};
      if (!NGUARD || n_g < N) val = *(const u16x8*)(B + (size_t)n_g*K + k0);
      int phys = s ^ ((br >> 1) & 7);
      *(u16x8*)&Bs[br*BK + phys*8] = val;
    }
    __syncthreads();
    #pragma unroll
    for (int ks = 0; ks < 2; ++ks){
      s16x8 a[MF], b[NF];
      #pragma unroll
      for (int i = 0; i < MF; ++i){
        int row = m0 + i*16 + (lane & 15);
        int phys = (ks*4 + (lane >> 4)) ^ ((row >> 1) & 7);
        a[i] = *(const s16x8*)&As[row*BK + phys*8];
      }
      #pragma unroll
      for (int j = 0; j < NF; ++j){
        int row = n0 + j*16 + (lane & 15);
        int phys = (ks*4 + (lane >> 4)) ^ ((row >> 1) & 7);
        b[j] = *(const s16x8*)&Bs[row*BK + phys*8];
      }
      #pragma unroll
      for (int i = 0; i < MF; ++i)
        #pragma unroll
        for (int j = 0; j < NF; ++j)
          acc[i][j] = __builtin_amdgcn_mfma_f32_16x16x32_bf16(a[i], b[j], acc[i][j], 0, 0, 0);
    }
    __syncthreads();
  }

  if constexpr (CMODE == 3){
    float* Cf = (float*)Cv;
    #pragma unroll
    for (int i = 0; i < MF; ++i)
      #pragma unroll
      for (int j = 0; j < NF; ++j){
        int col = bn + n0 + j*16 + (lane & 15);
        float bv = (bias && (!NGUARD || col < N)) ? bias[col] : 0.f;
        #pragma unroll
        for (int q = 0; q < 4; ++q){
          int row = bm + m0 + i*16 + (lane >> 4)*4 + q;
          float v = acc[i][j][q] + bv;
          if (RELU) v = fmaxf(v, 0.f);
          if (!NGUARD || col < N) Cf[(size_t)row*ldc + col] = v;
        }
      }
  } else {
    unsigned short* tile = As;
    #pragma unroll
    for (int i = 0; i < MF; ++i)
      #pragma unroll
      for (int j = 0; j < NF; ++j){
        int col = n0 + j*16 + (lane & 15);
        float bv = bias ? bias[bn + col] : 0.f;
        #pragma unroll
        for (int q = 0; q < 4; ++q){
          int row = m0 + i*16 + (lane >> 4)*4 + q;
          float v = acc[i][j][q] + bv;
          if (RELU) v = fmaxf(v, 0.f);
          tile[row*BN + col] = f2bf(v);
        }
      }
    __syncthreads();
    unsigned short* Cu = (unsigned short*)Cv;
    constexpr int CHUNKS = (BM*BN)/(256*8);
    #pragma unroll
    for (int c = 0; c < CHUNKS; ++c){
      int flat = tid*8 + c*2048;
      int row = flat / BN, col = flat - (flat/BN)*BN;
      u16x8 v = *(const u16x8*)&tile[flat];
      int rg = bm + row;
      size_t addr;
      if constexpr (CMODE == 0) addr = (size_t)rg*ldc + bn + col;
      else { int n = rg >> 4, p = rg & 15; addr = (size_t)n*cstride + p*64 + col; }
      *(u16x8*)&Cu[addr] = v;
    }
  }
}

// ---------------------------------------------------------------------------
// LSTM (r11 structure + VGPR pinning): one block per segment; both stacks.
// 256 threads (4 waves). e = tid>>1 (element, <100 active), sub = tid&1.
// sub0 owns full gate rows i(e), g(e); sub1 owns f(e), o(e) -- 100 packed
// f16-pair weight u32 per thread, PINNED in VGPRs via opaque asm.
// h: 50 packed u32 in LDS, read as 13 broadcast ds_read_b128 per wave.
// sub0 sends i*g via shfl_xor(1); sub1 holds c in a register, computes h,
// writes it to the double-buffered h (read t&1, write (t+1)&1): 1 barrier.
// L1a: batch x-part into LDS Xl1 (same-thread write/read, no barriers).
// Head fused.
// ---------------------------------------------------------------------------
#define PIN50(arr) _Pragma("unroll") \
  for (int _p = 0; _p < 50; ++_p){ asm volatile("" : "+v"(arr[_p])); }

__global__ __launch_bounds__(256,1) void lstm_k(
    const float* __restrict__ X0s, const float* __restrict__ X0r,
    const unsigned int* __restrict__ wpk,  // 6 x [50][400] u32 packed f16 pairs
    const float* __restrict__ s_bih0, const float* __restrict__ s_bhh0,
    const float* __restrict__ s_bih1, const float* __restrict__ s_bhh1,
    const float* __restrict__ r_bih0, const float* __restrict__ r_bhh0,
    const float* __restrict__ r_bih1, const float* __restrict__ r_bhh1,
    const float* __restrict__ f1w, const float* __restrict__ f1b,
    const float* __restrict__ f2w, const float* __restrict__ f2b,
    float* __restrict__ out)
{
  __shared__ alignas(16) unsigned int h0p[2][56];   // dbuf, 50 pairs (+pad)
  __shared__ alignas(16) unsigned int h1p[2][56];
  __shared__ alignas(16) unsigned int hbufp[1792];  // 32 steps x 56 pairs
  __shared__ alignas(16) float Xl1[12800];          // layer-1 x-part, 32 x 400
  __shared__ float xin[200];                        // head input [outR|outS]
  __shared__ float mid[512];                        // head hidden

  const int b = blockIdx.x, tid = threadIdx.x;
  const int e = tid >> 1, sub = tid & 1;
  const bool act = (e < 100);
  const int eS = act ? e : 0;            // clamped for safe addressing
  const int gA = sub*100 + eS;           // sub0: i-gate, sub1: f-gate
  const int gB = gA + 200;               // sub0: g-gate, sub1: o-gate

  if (tid < 56){ h0p[0][tid]=0u; h0p[1][tid]=0u; h1p[0][tid]=0u; h1p[1][tid]=0u; }
  for (int q = tid; q < 1792; q += 256) hbufp[q] = 0u;
  float c0r = 0.f, c1r = 0.f;
  __syncthreads();

  #pragma unroll 1
  for (int s = 0; s < 2; ++s){
    const float* Xp = (s ? X0r : X0s) + (size_t)b*32*400;
    const unsigned int* w0P  = wpk + (size_t)(s ? 3 : 0)*20000;
    const unsigned int* w1xP = wpk + (size_t)(s ? 4 : 1)*20000;
    const unsigned int* w1hP = wpk + (size_t)(s ? 5 : 2)*20000;
    const float* bi0 = s ? r_bih0 : s_bih0;
    const float* bh0 = s ? r_bhh0 : s_bhh0;
    const float* bi1 = s ? r_bih1 : s_bih1;
    const float* bh1 = s ? r_bhh1 : s_bhh1;

    // ------------- layer 0 (recurrent; 1 barrier/step) -------------
    {
      unsigned int wA[50], wB[50];
      #pragma unroll
      for (int p = 0; p < 50; ++p){
        wA[p] = w0P[p*400 + gA];
        wB[p] = w0P[p*400 + gB];
      }
      PIN50(wA); PIN50(wB);
      float bsA = bi0[gA] + bh0[gA];
      float bsB = bi0[gB] + bh0[gB];
      float xcA = Xp[gA], xcB = Xp[gB], xnA, xnB;
      #pragma unroll 1
      for (int t = 0; t < 32; ++t){
        if (t < 31){ xnA = Xp[(t+1)*400 + gA]; xnB = Xp[(t+1)*400 + gB]; }
        const u32x4* h4 = (const u32x4*)h0p[t & 1];
        float a0=0.f, a1=0.f, b0=0.f, b1=0.f;
        #pragma unroll
        for (int i = 0; i < 12; ++i){
          u32x4 hv = h4[i];
          a0 = dot2h(wA[4*i+0], hv[0], a0);
          a1 = dot2h(wA[4*i+1], hv[1], a1);
          a0 = dot2h(wA[4*i+2], hv[2], a0);
          a1 = dot2h(wA[4*i+3], hv[3], a1);
          b0 = dot2h(wB[4*i+0], hv[0], b0);
          b1 = dot2h(wB[4*i+1], hv[1], b1);
          b0 = dot2h(wB[4*i+2], hv[2], b0);
          b1 = dot2h(wB[4*i+3], hv[3], b1);
        }
        { u32x4 hv = h4[12];
          a0 = dot2h(wA[48], hv[0], a0);
          a1 = dot2h(wA[49], hv[1], a1);
          b0 = dot2h(wB[48], hv[0], b0);
          b1 = dot2h(wB[49], hv[1], b1);
        }
        float preA = (a0 + a1) + xcA + bsA;
        float preB = (b0 + b1) + xcB + bsB;
        float vA = sigmoidf_(preA);                       // i (sub0) / f (sub1)
        float vB = sub ? sigmoidf_(preB) : tanhf_(preB);  // o (sub1) / g (sub0)
        float send = vA * vB;                             // sub0: i*g
        float recv = __shfl_xor(send, 1);
        if (act && sub){
          c0r = vA*c0r + recv;
          float hn = vB * tanhf_(c0r);
          unsigned short hv16 = f2h(hn);
          ((unsigned short*)h0p[(t+1) & 1])[e] = hv16;
          ((unsigned short*)hbufp)[t*112 + e] = hv16;
        }
        xcA = xnA; xcB = xnB;
        __syncthreads();
      }
    }
    // ------- layer 1a: x-part pre-acts (batch; same-thread LDS, no barrier) -------
    {
      unsigned int wA[50], wB[50];
      #pragma unroll
      for (int p = 0; p < 50; ++p){
        wA[p] = w1xP[p*400 + gA];
        wB[p] = w1xP[p*400 + gB];
      }
      PIN50(wA); PIN50(wB);
      float bsA = bi1[gA] + bh1[gA];
      float bsB = bi1[gB] + bh1[gB];
      #pragma unroll 1
      for (int t = 0; t < 32; ++t){
        const u32x4* x4 = (const u32x4*)&hbufp[t*56];
        float a0=0.f, a1=0.f, b0=0.f, b1=0.f;
        #pragma unroll
        for (int i = 0; i < 12; ++i){
          u32x4 hv = x4[i];
          a0 = dot2h(wA[4*i+0], hv[0], a0);
          a1 = dot2h(wA[4*i+1], hv[1], a1);
          a0 = dot2h(wA[4*i+2], hv[2], a0);
          a1 = dot2h(wA[4*i+3], hv[3], a1);
          b0 = dot2h(wB[4*i+0], hv[0], b0);
          b1 = dot2h(wB[4*i+1], hv[1], b1);
          b0 = dot2h(wB[4*i+2], hv[2], b0);
          b1 = dot2h(wB[4*i+3], hv[3], b1);
        }
        { u32x4 hv = x4[12];
          a0 = dot2h(wA[48], hv[0], a0);
          a1 = dot2h(wA[49], hv[1], a1);
          b0 = dot2h(wB[48], hv[0], b0);
          b1 = dot2h(wB[49], hv[1], b1);
        }
        if (act){
          Xl1[t*400 + gA] = (a0 + a1) + bsA;
          Xl1[t*400 + gB] = (b0 + b1) + bsB;
        }
      }
    }
    // ------------- layer 1b: recurrent (1 barrier/step) -------------
    {
      unsigned int wA[50], wB[50];
      #pragma unroll
      for (int p = 0; p < 50; ++p){
        wA[p] = w1hP[p*400 + gA];
        wB[p] = w1hP[p*400 + gB];
      }
      PIN50(wA); PIN50(wB);
      #pragma unroll 1
      for (int t = 0; t < 32; ++t){
        const u32x4* h4 = (const u32x4*)h1p[t & 1];
        float a0=0.f, a1=0.f, b0=0.f, b1=0.f;
        #pragma unroll
        for (int i = 0; i < 12; ++i){
          u32x4 hv = h4[i];
          a0 = dot2h(wA[4*i+0], hv[0], a0);
          a1 = dot2h(wA[4*i+1], hv[1], a1);
          a0 = dot2h(wA[4*i+2], hv[2], a0);
          a1 = dot2h(wA[4*i+3], hv[3], a1);
          b0 = dot2h(wB[4*i+0], hv[0], b0);
          b1 = dot2h(wB[4*i+1], hv[1], b1);
          b0 = dot2h(wB[4*i+2], hv[2], b0);
          b1 = dot2h(wB[4*i+3], hv[3], b1);
        }
        { u32x4 hv = h4[12];
          a0 = dot2h(wA[48], hv[0], a0);
          a1 = dot2h(wA[49], hv[1], a1);
          b0 = dot2h(wB[48], hv[0], b0);
          b1 = dot2h(wB[49], hv[1], b1);
        }
        float preA = (a0 + a1) + Xl1[t*400 + gA];
        float preB = (b0 + b1) + Xl1[t*400 + gB];
        float vA = sigmoidf_(preA);
        float vB = sub ? sigmoidf_(preB) : tanhf_(preB);
        float send = vA * vB;
        float recv = __shfl_xor(send, 1);
        if (act && sub){
          c1r = vA*c1r + recv;
          float hn = vB * tanhf_(c1r);
          ((unsigned short*)h1p[(t+1) & 1])[e] = f2h(hn);
          if (t == 31){
            if (s) xin[e] = hn;          // outR -> head cols [0,100)
            else   xin[100 + e] = hn;    // outS -> head cols [100,200)
          }
        }
        __syncthreads();
      }
    }
  }

  // ------------- fused head: out[b] = relu(xin@f1w^T+b1)@f2w^T+b2 -------------
  for (int r = tid; r < 512; r += 256){
    float acc = f1b[r];
    const float* wrow = f1w + (size_t)r*200;
    #pragma unroll 4
    for (int k = 0; k < 200; ++k) acc += xin[k]*wrow[k];
    mid[r] = fmaxf(acc, 0.f);
  }
  __syncthreads();
  if (tid < 130){
    float acc = f2b[tid];
    const float* wrow = f2w + (size_t)tid*512;
    #pragma unroll 4
    for (int k = 0; k < 512; ++k) acc += mid[k]*wrow[k];
    out[b*130 + tid] = acc;
  }
}

extern "C" void kernel_launch(void* const* d_in, const int* in_sizes, int n_in,
                              void* d_out, int out_size, void* d_ws, size_t ws_size,
                              hipStream_t stream)
{
  const float* obs  = (const float*)d_in[0];
  const float* data = (const float*)d_in[1];
  const float* c1w = (const float*)d_in[2];  const float* c1b = (const float*)d_in[3];
  const float* c2w = (const float*)d_in[4];  const float* c2b = (const float*)d_in[5];
  const float* c3w = (const float*)d_in[6];  const float* c3b = (const float*)d_in[7];
  const float* l1w = (const float*)d_in[8];  const float* l1b = (const float*)d_in[9];
  const float* l2w = (const float*)d_in[10]; const float* l2b = (const float*)d_in[11];
  const float* s_wih0=(const float*)d_in[12]; const float* s_whh0=(const float*)d_in[13];
  const float* s_bih0=(const float*)d_in[14]; const float* s_bhh0=(const float*)d_in[15];
  const float* s_wih1=(const float*)d_in[16]; const float* s_whh1=(const float*)d_in[17];
  const float* s_bih1=(const float*)d_in[18]; const float* s_bhh1=(const float*)d_in[19];
  const float* r_wih0=(const float*)d_in[20]; const float* r_whh0=(const float*)d_in[21];
  const float* r_bih0=(const float*)d_in[22]; const float* r_bhh0=(const float*)d_in[23];
  const float* r_wih1=(const float*)d_in[24]; const float* r_whh1=(const float*)d_in[25];
  const float* r_bih1=(const float*)d_in[26]; const float* r_bhh1=(const float*)d_in[27];
  const float* f1w=(const float*)d_in[28]; const float* f1b=(const float*)d_in[29];
  const float* f2w=(const float*)d_in[30]; const float* f2b=(const float*)d_in[31];
  float* out = (float*)d_out;
  (void)in_sizes; (void)n_in; (void)out_size;

  // ---- workspace layout (bytes, 256-aligned); total ~ 67 MB ----
  char* p = (char*)d_ws;
  auto alloc = [&](size_t bytes){ void* r = (void*)p; p += (bytes + 255) & ~(size_t)255; return r; };
  unsigned short* data_bf = (unsigned short*)alloc((size_t)2048*1536*2);
  unsigned short* c1w_bf  = (unsigned short*)alloc((size_t)32*192*2);
  unsigned short* c2w_bf  = (unsigned short*)alloc((size_t)64*512*2);
  unsigned short* c3w_bf  = (unsigned short*)alloc((size_t)64*576*2);
  unsigned short* l1w_bf  = (unsigned short*)alloc((size_t)1024*1536*2);
  unsigned short* l2w_bf  = (unsigned short*)alloc((size_t)512*1024*2);
  unsigned short* wihS_bf = (unsigned short*)alloc((size_t)400*1536*2);
  unsigned short* wihR_bf = (unsigned short*)alloc((size_t)400*1536*2);
  unsigned short* conv1o  = (unsigned short*)alloc((size_t)2048*225*32*2);  // NHWC
  unsigned short* conv2o  = (unsigned short*)alloc((size_t)2048*36*64*2);   // NHWC
  unsigned short* feat    = (unsigned short*)alloc((size_t)2048*1536*2);
  unsigned short* lin1o   = (unsigned short*)alloc((size_t)2048*1024*2);
  float* X0s  = (float*)alloc((size_t)1024*400*4);
  float* X0r  = (float*)alloc((size_t)1024*400*4);
  unsigned int* wpk = (unsigned int*)alloc((size_t)6*20000*4);
  (void)ws_size;

  // ---- merged prep (1 launch) ----
  prep_k<<<dim3(512,9),256,0,stream>>>(
      data, data_bf, l1w, l1w_bf, l2w, l2w_bf, c1w, c1w_bf,
      c2w, c2w_bf, c3w, c3w_bf, s_wih0, wihS_bf, r_wih0, wihR_bf,
      s_whh0, s_wih1, s_whh1, r_whh0, r_wih1, r_whh1, wpk);

  // ---- GEMM chain (bf16 MFMA, fp32 accumulate) ----
  mgemm<128,32,4,1, 1,0,1,0, 3,64,64,8,8,4,15,15><<<dim3(3600,1),256,0,stream>>>(
      obs, c1w_bf, conv1o, c1b, 460800, 32, 192, 0, 32, 0);
  mgemm<128,64,2,2, 2,0,1,0, 32,15,15,4,4,2,6,6><<<dim3(576,1),256,0,stream>>>(
      conv1o, c2w_bf, conv2o, c2b, 73728, 64, 512, 0, 64, 0);
  mgemm<128,64,2,2, 0,0,1,0, 1,1,1,1,1,1,1,1><<<dim3(16,16),256,0,stream>>>(
      data_bf, l1w_bf, lin1o, l1b, 2048, 1024, 1536, 1536, 1024, 0);
  mgemm<128,64,2,2, 2,2,1,0, 64,6,6,3,3,1,4,4><<<dim3(256,1),256,0,stream>>>(
      conv2o, c3w_bf, feat, c3b, 32768, 64, 576, 0, 0, 1536);
  mgemm<128,64,2,2, 0,0,0,0, 1,1,1,1,1,1,1,1><<<dim3(16,8),256,0,stream>>>(
      lin1o, l2w_bf, feat + 1024, l2b, 2048, 512, 1024, 1024, 1536, 0);
  mgemm<128,64,2,2, 0,3,0,1, 1,1,1,1,1,1,1,1><<<dim3(8,7),256,0,stream>>>(
      feat, wihS_bf, X0s, (const float*)nullptr, 1024, 400, 1536, 1536, 400, 0);
  mgemm<128,64,2,2, 0,3,0,1, 1,1,1,1,1,1,1,1><<<dim3(8,7),256,0,stream>>>(
      feat + (size_t)1024*1536, wihR_bf, X0r, (const float*)nullptr, 1024, 400, 1536, 1536, 400, 0);

  // ---- sequential LSTM + fused head ----
  lstm_k<<<32,256,0,stream>>>(X0s, X0r, wpk,
                              s_bih0,s_bhh0,s_bih1,s_bhh1,
                              r_bih0,r_bhh0,r_bih1,r_bhh1,
                              f1w, f1b, f2w, f2b, out);
}